// Round 6
// baseline (2244.632 us; speedup 1.0000x reference)
//
#include <hip/hip_runtime.h>
#include <hip/hip_bf16.h>
#include <math.h>

// Problem dims (fixed by the reference)
#define RB 64
#define RS 512
#define RE 1024
#define RH 1024
#define BSH ((size_t)RB * RS * RH)

// scan decomposition: 256 blocks = 64 col-groups x 4 row-groups.
// The 4 row groups are INDEPENDENT scans (disjoint batch rows).
// Sync (proven in round 5): each block owns flag SLOT rg*64+cg. flag[slot]=g
// means that block finished step g-2 and its h3_{g-1} agent-scope publishes
// are visible at L3 (flag stored after a __syncthreads that drains vmcnt).
// Consumer at step t polls its row group's 64 contiguous slots with ONE
// coalesced wave load (lane l = cg l) and __all(f >= t+1). Flag t+1 also
// proves that block finished its step t-1 READS of buffer (t-1)&1, so
// writing h3_{t+1} into buffer (t+1)&1 during step t never overwrites
// unread data (ping-pong induction).
//
// Round-6 changes (publication-chain surgery, protocol unchanged):
//  * 128-thread blocks (2 waves, K=512/wave, ufr[16]) — fewer barriers,
//    2-way LDS reduce, 16 frag loads issued in ONE burst (64 VGPRs in flight).
//  * wx prefetch issued at TOP of step (drains under compute, not under the
//    publish barrier).
//  * Epilogue: tanh -> h3 stores -> __syncthreads (drains ONLY h3 flight)
//    -> flag -> DEFERRED Out HBM stores (overlap next step's poll).
//  * red[] parity double-buffered: one reduce barrier per step.
#define NBLK 256

typedef __attribute__((ext_vector_type(8))) __bf16 bf16x8;
typedef __attribute__((ext_vector_type(4))) float  f32x4;

__device__ __forceinline__ bf16x8 cvt8(f32x4 a, f32x4 b) {
    bf16x8 r;
    r[0] = (__bf16)a[0]; r[1] = (__bf16)a[1];
    r[2] = (__bf16)a[2]; r[3] = (__bf16)a[3];
    r[4] = (__bf16)b[0]; r[5] = (__bf16)b[1];
    r[6] = (__bf16)b[2]; r[7] = (__bf16)b[3];
    return r;
}

// L2-bypassing (agent-scope => L3 coherent point) accessors for cross-XCD data.
__device__ __forceinline__ bf16x8 ld_frag_agent(const unsigned long long* p) {
    union { unsigned long long u[2]; bf16x8 v; } r;
    r.u[0] = __hip_atomic_load(p,     __ATOMIC_RELAXED, __HIP_MEMORY_SCOPE_AGENT);
    r.u[1] = __hip_atomic_load(p + 1, __ATOMIC_RELAXED, __HIP_MEMORY_SCOPE_AGENT);
    return r.v;
}
__device__ __forceinline__ void st_bf16_agent(__bf16* p, float v) {
    union { __bf16 b; unsigned short s; } u;
    u.b = (__bf16)v;
    __hip_atomic_store(reinterpret_cast<unsigned short*>(p), u.s,
                       __ATOMIC_RELAXED, __HIP_MEMORY_SCOPE_AGENT);
}

// ---------------------------------------------------------------------------
// Phase 0: zero the 256 progress flags (d_ws is re-poisoned each call).
// ---------------------------------------------------------------------------
__global__ void init_flags_k(unsigned* flags) {
    if (threadIdx.x < NBLK) flags[threadIdx.x] = 0u;
}

// ---------------------------------------------------------------------------
// Phase 1: wx[m,h] = sum_e x[m,e]*W_w[h,e] + W_b[h]
// 128x128 tile, BK=64, reg-staged fp32->bf16 into padded LDS, 2x2 wave grid,
// 4x4 16x16x32 MFMA fragments per wave. (unchanged — known good)
// ---------------------------------------------------------------------------
#define WBK  64
#define LDST 72   // 64 + 8 pad bf16 elems; 144 B row stride (16B-aligned)

__global__ __launch_bounds__(256) void wx_gemm(
    const float* __restrict__ X,
    const float* __restrict__ Ww,
    const float* __restrict__ Wb,
    float* __restrict__ Out)
{
    __shared__ __align__(16) __bf16 As[128 * LDST];
    __shared__ __align__(16) __bf16 Bs[128 * LDST];

    const int tid  = threadIdx.x;
    const int lane = tid & 63;
    const int wave = tid >> 6;
    const int m0   = blockIdx.y * 128;
    const int n0   = blockIdx.x * 128;
    const int wm   = (wave >> 1) * 64;
    const int wn   = (wave & 1) * 64;

    const int sk   = (tid & 7) * 8;
    const int srow = tid >> 3;

    f32x4 acc[4][4];
#pragma unroll
    for (int i = 0; i < 4; ++i)
#pragma unroll
        for (int j = 0; j < 4; ++j) acc[i][j] = (f32x4){0.f, 0.f, 0.f, 0.f};

    for (int kc = 0; kc < RE; kc += WBK) {
#pragma unroll
        for (int rr = 0; rr < 128; rr += 32) {
            const float* xp = X + (size_t)(m0 + srow + rr) * RE + kc + sk;
            *reinterpret_cast<bf16x8*>(&As[(srow + rr) * LDST + sk]) =
                cvt8(*reinterpret_cast<const f32x4*>(xp),
                     *reinterpret_cast<const f32x4*>(xp + 4));
            const float* wp = Ww + (size_t)(n0 + srow + rr) * RE + kc + sk;
            *reinterpret_cast<bf16x8*>(&Bs[(srow + rr) * LDST + sk]) =
                cvt8(*reinterpret_cast<const f32x4*>(wp),
                     *reinterpret_cast<const f32x4*>(wp + 4));
        }
        __syncthreads();

#pragma unroll
        for (int ks = 0; ks < 2; ++ks) {
            bf16x8 af[4], bfr[4];
#pragma unroll
            for (int i = 0; i < 4; ++i) {
                af[i]  = *reinterpret_cast<const bf16x8*>(
                    &As[(wm + i * 16 + (lane & 15)) * LDST + ks * 32 + (lane >> 4) * 8]);
                bfr[i] = *reinterpret_cast<const bf16x8*>(
                    &Bs[(wn + i * 16 + (lane & 15)) * LDST + ks * 32 + (lane >> 4) * 8]);
            }
#pragma unroll
            for (int i = 0; i < 4; ++i)
#pragma unroll
                for (int j = 0; j < 4; ++j)
                    acc[i][j] = __builtin_amdgcn_mfma_f32_16x16x32_bf16(
                        af[i], bfr[j], acc[i][j], 0, 0, 0);
        }
        __syncthreads();
    }

    const int col = lane & 15, rbase = (lane >> 4) * 4;
#pragma unroll
    for (int j = 0; j < 4; ++j) {
        const int n = n0 + wn + j * 16 + col;
        const float bias = Wb[n];
#pragma unroll
        for (int i = 0; i < 4; ++i) {
#pragma unroll
            for (int r = 0; r < 4; ++r) {
                const int m = m0 + wm + i * 16 + rbase + r;
                Out[(size_t)m * RH + n] = acc[i][j][r] + bias;
            }
        }
    }
}

// ---------------------------------------------------------------------------
// Phase 2: persistent scan, 256 blocks x 128 thr (2 waves).
// Block (cg,rg) owns the 16x16 output patch rows [16rg,+16) x cols [16cg,+16).
// Wave w covers K in [512w, 512w+512): ufr[16] (64 VGPR), 16 frag loads per
// step issued as one burst. 2-way K reduction through parity-buffered LDS.
// ---------------------------------------------------------------------------
__global__ __launch_bounds__(128) void rnn_scan(
    const float* __restrict__ Uw,
    const float* __restrict__ Ub,
    float* Out,               // [B*S*H] (wx -> result1) then [B*H] t_final
    __bf16* hbuf,             // 2 * B * H bf16, double-buffered h3 (256 KB)
    unsigned* flags)          // 256 progress flags (1 KB), slot = rg*64+cg
{
    __shared__ float red[2][2][256];     // [parity][wave][row*16+col]

    const int tid  = threadIdx.x;
    const int lane = tid & 63;
    const int wave = tid >> 6;           // K-half index 0..1
    const int bid  = blockIdx.x;
    const int cg   = bid >> 2;           // column group 0..63
    const int rg   = bid & 3;            // row group 0..3 (independent scan)
    const int col0 = cg * 16;
    const int row0 = rg * 16;
    const int slot = rg * 64 + cg;       // this block's flag slot

    // --- register-resident U^T slice for this wave's K half ---
    // B-frag layout: n = lane&15, k = 512*wave + 32*j + (lane>>4)*8
    bf16x8 ufr[16];
    {
        const float* up = Uw + (size_t)(col0 + (lane & 15)) * RH
                        + 512 * wave + ((lane >> 4) * 8);
#pragma unroll
        for (int j = 0; j < 16; ++j)
            ufr[j] = cvt8(*reinterpret_cast<const f32x4*>(up + j * 32),
                          *reinterpret_cast<const f32x4*>(up + j * 32 + 4));
    }

    // epilogue mapping: thread handles patch indices tid and tid+128
    // idx -> (row = idx>>4, col = idx&15); idx+128 is row+8, same col.
    const int e0row = row0 + (tid >> 4);
    const int e1row = e0row + 8;
    const int ecol  = col0 + (tid & 15);
    const float ub  = Ub[ecol];

    // --- h3_0 = tanh(wx[:, 0, patch]) into buffer 0, then flag = 1 ---
    {
        const float w0 = Out[(size_t)e0row * RS * RH + ecol];
        const float w1 = Out[(size_t)e1row * RS * RH + ecol];
        st_bf16_agent(hbuf + e0row * RH + ecol, tanhf(w0));
        st_bf16_agent(hbuf + e1row * RH + ecol, tanhf(w1));
    }
    __syncthreads();                         // drains the h3_0 stores (vmcnt)
    if (tid == 0)
        __hip_atomic_store(&flags[slot], 1u,
                           __ATOMIC_RELAXED, __HIP_MEMORY_SCOPE_AGENT);

    const int arow  = row0 + (lane & 15);          // batch row for A-frags
    const int kbase = 512 * wave + (lane >> 4) * 8;
    const unsigned* myflags = flags + rg * 64;     // this row group's 64 slots

    for (int t = 0; t < RS; ++t) {
        const __bf16* cur = hbuf + (size_t)(t & 1) * (RB * RH);
        __bf16*       nxt = hbuf + (size_t)((t + 1) & 1) * (RB * RH);
        const unsigned long long* cp =
            reinterpret_cast<const unsigned long long*>(cur)
            + ((size_t)arow * RH + kbase) / 4;

        // --- wx(t+1) prefetch issued at TOP of step: the cold HBM read
        // drains under the poll + frag loads + MFMA, and is complete well
        // before its use in the epilogue tanh. Never sits in the publish
        // barrier's vmcnt drain.
        float wn0 = 0.f, wn1 = 0.f;
        if (t < RS - 1) {
            wn0 = Out[(size_t)e0row * RS * RH + (size_t)(t + 1) * RH + ecol];
            wn1 = Out[(size_t)e1row * RS * RH + (size_t)(t + 1) * RH + ecol];
        }

        // --- poll: one coalesced wave load of the 64 slots, all >= t+1 ---
        const unsigned tgt = (unsigned)(t + 1);
        while (true) {
            const unsigned f = __hip_atomic_load(&myflags[lane],
                                                 __ATOMIC_RELAXED,
                                                 __HIP_MEMORY_SCOPE_AGENT);
            if (__all(f >= tgt)) break;
            __builtin_amdgcn_s_sleep(1);
        }
        // acquire-substitute: forbid the compiler from hoisting the frag
        // loads above the relaxed spin (HW issue is in-order).
        __builtin_amdgcn_sched_barrier(0);
        asm volatile("" ::: "memory");

        // --- 16 A-frag loads (32 u64, L3): ONE burst, all in flight ---
        bf16x8 x[16];
#pragma unroll
        for (int f = 0; f < 16; ++f)
            x[f] = ld_frag_agent(cp + f * 8);

        f32x4 ac0 = (f32x4){0.f, 0.f, 0.f, 0.f};
        f32x4 ac1 = ac0, ac2 = ac0, ac3 = ac0;
#pragma unroll
        for (int f = 0; f < 16; f += 4) {
            ac0 = __builtin_amdgcn_mfma_f32_16x16x32_bf16(x[f + 0], ufr[f + 0], ac0, 0, 0, 0);
            ac1 = __builtin_amdgcn_mfma_f32_16x16x32_bf16(x[f + 1], ufr[f + 1], ac1, 0, 0, 0);
            ac2 = __builtin_amdgcn_mfma_f32_16x16x32_bf16(x[f + 2], ufr[f + 2], ac2, 0, 0, 0);
            ac3 = __builtin_amdgcn_mfma_f32_16x16x32_bf16(x[f + 3], ufr[f + 3], ac3, 0, 0, 0);
        }
        const f32x4 acc = (ac0 + ac1) + (ac2 + ac3);

        // --- 2-way cross-wave K reduction, parity-buffered (1 barrier) ---
        {
            float* rb = red[t & 1][wave];
#pragma unroll
            for (int r = 0; r < 4; ++r)
                rb[((lane >> 4) * 4 + r) * 16 + (lane & 15)] = acc[r];
        }
        __syncthreads();
        const float* r0 = red[t & 1][0];
        const float* r1 = red[t & 1][1];
        const float v0 = r0[tid]       + r1[tid]       + ub;
        const float v1 = r0[tid + 128] + r1[tid + 128] + ub;

        const size_t o0 = (size_t)e0row * RS * RH + (size_t)t * RH + ecol;
        const size_t o1 = (size_t)e1row * RS * RH + (size_t)t * RH + ecol;
        if (t == RS - 1) {
            Out[o0] = v0;
            Out[o1] = v1;
            Out[BSH + (size_t)e0row * RH + ecol] = v0;    // t_final
            Out[BSH + (size_t)e1row * RH + ecol] = v1;
        } else {
            // publication chain: tanh -> h3 stores -> barrier (drains ONLY
            // these stores) -> flag. Out HBM stores are DEFERRED after the
            // flag so they overlap the next step's poll wait.
            st_bf16_agent(nxt + e0row * RH + ecol, tanhf(wn0 + v0));
            st_bf16_agent(nxt + e1row * RH + ecol, tanhf(wn1 + v1));
            __syncthreads();                 // drains h3 publishes (vmcnt)
            if (tid == 0)
                __hip_atomic_store(&flags[slot], (unsigned)(t + 2),
                                   __ATOMIC_RELAXED, __HIP_MEMORY_SCOPE_AGENT);
            Out[o0] = v0;
            Out[o1] = v1;
        }
    }
}

// ---------------------------------------------------------------------------
extern "C" void kernel_launch(void* const* d_in, const int* in_sizes, int n_in,
                              void* d_out, int out_size, void* d_ws, size_t ws_size,
                              hipStream_t stream)
{
    const float* X  = (const float*)d_in[0];   // [B,S,E] fp32
    const float* Ww = (const float*)d_in[1];   // [H,E]   fp32
    const float* Wb = (const float*)d_in[2];   // [H]     fp32
    const float* Uw = (const float*)d_in[3];   // [H,H]   fp32
    const float* Ub = (const float*)d_in[4];   // [H]     fp32
    float* Out = (float*)d_out;                // [B*S*H] result1 + [B*H] t_final

    __bf16* hbuf = (__bf16*)d_ws;              // 2*B*H bf16 = 256 KB
    unsigned* flags = (unsigned*)((char*)d_ws + (size_t)2 * RB * RH * sizeof(__bf16));

    hipLaunchKernelGGL(init_flags_k, dim3(1), dim3(256), 0, stream, flags);
    hipLaunchKernelGGL(wx_gemm, dim3(RH / 128, (RB * RS) / 128), dim3(256), 0, stream,
                       X, Ww, Wb, Out);
    hipLaunchKernelGGL(rnn_scan, dim3(NBLK), dim3(128), 0, stream,
                       Uw, Ub, Out, hbuf, flags);
}